// Round 9
// baseline (75.637 us; speedup 1.0000x reference)
//
#include <hip/hip_runtime.h>
#include <stdint.h>

// quantizer_channel: out[e] = center[ nearest_idx(x[e]) ^ noise_mask(e) ]
//
// nearest_idx == jnp.argmin(|x-center|) exactly, via sorted binary search;
// 15 thresholds bit-bisected in a setup kernel against the reference
// predicate (f32 distances, first-original-index tie-break).
// noise bits == jax.random.bernoulli(key(42), .01, [B,C,H,W,4]) under
// partitionable threefry2x32: draw i = w0^w1 of threefry2x32((0,42),(0,i));
// bit = draw < (83887u<<9).   [absmax=0 verified R1-R8]
//
// R9: R6 fused structure + persistent grid (2048 blocks = 8/CU, waves stay
// resident, 16x fewer dispatches) + next-iteration x prefetch under the
// ~1200-op threefry body. Threefry issue is the measured floor (R7: 66us
// standalone; chip practical VALU issue ~3 cyc/wave-instr, m07).

#define KS1 42u
#define KS2 0x1BD11BF0u   // 0x1BD11BDA ^ 0 ^ 42
#define BERN_LT 42950144u // 83887 << 9

// ---------- ordered-float <-> key ----------------------------------------
__device__ __forceinline__ uint32_t fkey(float f) {
  uint32_t u = __float_as_uint(f);
  return (u & 0x80000000u) ? ~u : (u | 0x80000000u);
}
__device__ __forceinline__ float finv(uint32_t k) {
  uint32_t u = (k & 0x80000000u) ? (k & 0x7fffffffu) : ~k;
  return __uint_as_float(u);
}

// ---------- setup: sort centers, bisect exact cell thresholds -------------
// ws words: [0..14]=T0..T14  [15]=pad  [16..31]=sidx[rank]
__global__ void quantizer_setup_kernel(const float* __restrict__ center,
                                       float* __restrict__ ws) {
  const int t = threadIdx.x;
  __shared__ float sval[16];
  __shared__ int   sidx[16];
  if (t < 16) {
    const float ct = center[t];
    int rank = 0;
    for (int j = 0; j < 16; ++j) {
      const float cj = center[j];
      rank += (cj < ct || (cj == ct && j < t)) ? 1 : 0;
    }
    sval[rank] = ct;
    sidx[rank] = t;
  }
  __syncthreads();
  if (t < 15) {
    const float sL = sval[t], sR = sval[t + 1];
    const bool tieLeft = sidx[t] < sidx[t + 1];
    uint32_t lo = fkey(sL), hi = fkey(sR);
    while (hi - lo > 1u) {
      const uint32_t mid = lo + ((hi - lo) >> 1);
      const float xm = finv(mid);
      const float dL = fabsf(xm - sL);
      const float dR = fabsf(xm - sR);
      const bool left = (dL < dR) || (dL == dR && tieLeft);
      if (left) lo = mid; else hi = mid;
    }
    ws[t] = finv(lo);
  }
  __syncthreads();
  if (t < 16) {
    ((uint32_t*)ws)[16 + t] = (uint32_t)sidx[t];
    if (t == 15) ((uint32_t*)ws)[15] = 0u;
  }
}

// ---------- threefry helpers ----------------------------------------------
__device__ __forceinline__ uint32_t rotl(uint32_t x, int r) {
  return __builtin_amdgcn_alignbit(x, x, (32 - r) & 31);
}
#define TF_ROUND4(r)                                            \
  { _Pragma("unroll") for (int j = 0; j < 4; ++j) {             \
      y0[j] += y1[j];                                           \
      y1[j] = rotl(y1[j], (r)) ^ y0[j];                         \
  } }
#define TF_INJ4(a, b)                                           \
  { _Pragma("unroll") for (int j = 0; j < 4; ++j) {             \
      y0[j] += (a); y1[j] += (b);                               \
  } }
// round 1 specialized for y0_init = 0 (y0 += y1 -> copy)
#define TF_BODY_FROM_CTR                                        \
  { _Pragma("unroll") for (int j = 0; j < 4; ++j) {             \
      y0[j] = y1[j];                                            \
      y1[j] = rotl(y1[j], 13) ^ y0[j];                          \
  } }                                                           \
  TF_ROUND4(15) TF_ROUND4(26) TF_ROUND4(6)                      \
  TF_INJ4(KS1, KS2 + 1u)                                        \
  TF_ROUND4(17) TF_ROUND4(29) TF_ROUND4(16) TF_ROUND4(24)      \
  TF_INJ4(KS2, 0u + 2u)                                         \
  TF_ROUND4(13) TF_ROUND4(15) TF_ROUND4(26) TF_ROUND4(6)       \
  TF_INJ4(0u, KS1 + 3u)                                         \
  TF_ROUND4(17) TF_ROUND4(29) TF_ROUND4(16) TF_ROUND4(24)      \
  TF_INJ4(KS1, KS2 + 4u)                                        \
  TF_ROUND4(13) TF_ROUND4(15) TF_ROUND4(26) TF_ROUND4(6)       \
  TF_INJ4(KS2, 0u + 5u)

// ---------- main: fused, persistent grid, prefetched grid-stride ----------
__global__ __launch_bounds__(256) void quantizer_channel_kernel(
    const float* __restrict__ x, const float* __restrict__ center,
    const float* __restrict__ ws, float* __restrict__ out,
    int n4, int stride)
{
  const int t0 = blockIdx.x * blockDim.x + threadIdx.x;

  const int lane   = threadIdx.x & 63;
  const int base_b = (lane & 48) << 2;           // bpermute base of own 16-group

  // per-lane crossbar tables (replicated every 16 lanes)
  const int ctab = __float_as_int(center[lane & 15]);            // idx -> value
  const int stab = (int)((const uint32_t*)ws)[16 + (lane & 15)]; // rank -> idx

  // thresholds (wave-uniform)
  const float4* wsf = (const float4*)ws;
  const float4 ta = wsf[0], tb = wsf[1], tc = wsf[2], td = wsf[3];
  const float T0 = ta.x, T1 = ta.y, T2  = ta.z, T3  = ta.w;
  const float T4 = tb.x, T5 = tb.y, T6  = tb.z, T7  = tb.w;
  const float T8 = tc.x, T9 = tc.y, T10 = tc.z, T11 = tc.w;
  const float T12 = td.x, T13 = td.y, T14 = td.z;

  const float4* __restrict__ x4  = reinterpret_cast<const float4*>(x);
  float4* __restrict__       out4 = reinterpret_cast<float4*>(out);

  if (t0 >= n4) return;
  float4 xv = x4[t0];                            // first prefetch

  for (int i = t0; i < n4; i += stride) {
    const float4 cur = xv;
    const int inext = i + stride;
    if (inext < n4) xv = x4[inext];              // prefetch under compute

    const float xe[4] = {cur.x, cur.y, cur.z, cur.w};
    float oe[4];
    const uint32_t cb = (uint32_t)i * 16u + KS1; // counter base + ks1

#pragma unroll
    for (int e = 0; e < 4; ++e) {
      // ---- threefry2x32 x4 chains, counters (0, 16i+4e+j)
      uint32_t y0[4], y1[4];
      const uint32_t c0 = cb + 4u * (uint32_t)e;
#pragma unroll
      for (int j = 0; j < 4; ++j) { y1[j] = c0 + (uint32_t)j; }
      TF_BODY_FROM_CTR

      // ---- flip nibble, MSB-first, addc-chain pack
      uint32_t f = 0u;
      f = f + f + (((y0[0] ^ y1[0]) < BERN_LT) ? 1u : 0u);
      f = f + f + (((y0[1] ^ y1[1]) < BERN_LT) ? 1u : 0u);
      f = f + f + (((y0[2] ^ y1[2]) < BERN_LT) ? 1u : 0u);
      f = f + f + (((y0[3] ^ y1[3]) < BERN_LT) ? 1u : 0u);

      // ---- exact nearest-center: 4-level select tree over sorted cells
      const float v = xe[e];
      const bool b3_ = v > T7;
      const float s2 = b3_ ? T11 : T3;
      const bool b2_ = v > s2;
      const float s1 = b3_ ? (b2_ ? T13 : T9) : (b2_ ? T5 : T1);
      const bool b1_ = v > s1;
      const float u0 = b1_ ? T2  : T0;
      const float u1 = b1_ ? T6  : T4;
      const float u2 = b1_ ? T10 : T8;
      const float u3 = b1_ ? T14 : T12;
      const float s0 = b3_ ? (b2_ ? u3 : u2) : (b2_ ? u1 : u0);
      const bool b0_ = v > s0;
      const uint32_t cell = (b3_ ? 8u : 0u) | (b2_ ? 4u : 0u) |
                            (b1_ ? 2u : 0u) | (b0_ ? 1u : 0u);

      // rank -> orig idx, then noisy idx -> value: register crossbar, no VMEM
      const int best = __builtin_amdgcn_ds_bpermute(base_b + (int)(cell << 2), stab);
      const int fin_addr = base_b + (int)((((uint32_t)best) ^ f) << 2);
      oe[e] = __int_as_float(__builtin_amdgcn_ds_bpermute(fin_addr, ctab));
    }

    float4 o4;
    o4.x = oe[0]; o4.y = oe[1]; o4.z = oe[2]; o4.w = oe[3];
    out4[i] = o4;
  }
}

extern "C" void kernel_launch(void* const* d_in, const int* in_sizes, int n_in,
                              void* d_out, int out_size, void* d_ws, size_t ws_size,
                              hipStream_t stream)
{
  const float* x      = (const float*)d_in[0];
  const float* center = (const float*)d_in[1];
  float* out          = (float*)d_out;
  float* ws           = (float*)d_ws;

  hipLaunchKernelGGL(quantizer_setup_kernel, dim3(1), dim3(64), 0, stream,
                     center, ws);

  const int N  = in_sizes[0];          // 8388608
  const int n4 = N / 4;                // 2097152 float4s
  const int block = 256;
  int grid = 2048;                     // 8 blocks/CU x 256 CUs, persistent
  const int maxg = (n4 + block - 1) / block;
  if (grid > maxg) grid = maxg;

  hipLaunchKernelGGL(quantizer_channel_kernel, dim3(grid), dim3(block), 0, stream,
                     x, center, ws, out, n4, grid * block);
}

// Round 10
// 72.725 us; speedup vs baseline: 1.0401x; 1.0401x over previous
//
#include <hip/hip_runtime.h>
#include <stdint.h>

// quantizer_channel: out[e] = center[ nearest_idx(x[e]) ^ noise_mask(e) ]
//
// nearest_idx == jnp.argmin(|x-center|) exactly, via sorted binary search;
// 15 thresholds bit-bisected in a setup kernel against the reference
// predicate (f32 distances, first-original-index tie-break).
// noise bits == jax.random.bernoulli(key(42), .01, [B,C,H,W,4]) under
// partitionable threefry2x32: draw i = w0^w1 of threefry2x32((0,42),(0,i));
// bit = draw < (83887u<<9).   [absmax=0 verified R1-R9]
//
// R10 (final): revert to the measured-best R6 structure (72.66 us).
// Attribution (R7 split): pure threefry = 66 us = 91% of runtime; issue-rate
// ~4.2 cyc/wave-instr vs chip-best 3.05 (m07). ILP restructure (R4), asm
// pinning (R5), block=1024 (R8), persistent+prefetch (R9) all <=0 gain.
// 33.5M spec-pinned threefry evaluations x 20 ARX rounds = the floor.

#define KS1 42u
#define KS2 0x1BD11BF0u   // 0x1BD11BDA ^ 0 ^ 42
#define BERN_LT 42950144u // 83887 << 9

// ---------- ordered-float <-> key ----------------------------------------
__device__ __forceinline__ uint32_t fkey(float f) {
  uint32_t u = __float_as_uint(f);
  return (u & 0x80000000u) ? ~u : (u | 0x80000000u);
}
__device__ __forceinline__ float finv(uint32_t k) {
  uint32_t u = (k & 0x80000000u) ? (k & 0x7fffffffu) : ~k;
  return __uint_as_float(u);
}

// ---------- setup: sort centers, bisect exact cell thresholds -------------
// ws words: [0..14]=T0..T14  [15]=pad  [16..31]=sidx[rank]
__global__ void quantizer_setup_kernel(const float* __restrict__ center,
                                       float* __restrict__ ws) {
  const int t = threadIdx.x;
  __shared__ float sval[16];
  __shared__ int   sidx[16];
  if (t < 16) {
    const float ct = center[t];
    int rank = 0;
    for (int j = 0; j < 16; ++j) {
      const float cj = center[j];
      rank += (cj < ct || (cj == ct && j < t)) ? 1 : 0;
    }
    sval[rank] = ct;
    sidx[rank] = t;
  }
  __syncthreads();
  if (t < 15) {
    const float sL = sval[t], sR = sval[t + 1];
    const bool tieLeft = sidx[t] < sidx[t + 1];
    uint32_t lo = fkey(sL), hi = fkey(sR);
    while (hi - lo > 1u) {
      const uint32_t mid = lo + ((hi - lo) >> 1);
      const float xm = finv(mid);
      const float dL = fabsf(xm - sL);
      const float dR = fabsf(xm - sR);
      const bool left = (dL < dR) || (dL == dR && tieLeft);
      if (left) lo = mid; else hi = mid;
    }
    ws[t] = finv(lo);
  }
  __syncthreads();
  if (t < 16) {
    ((uint32_t*)ws)[16 + t] = (uint32_t)sidx[t];
    if (t == 15) ((uint32_t*)ws)[15] = 0u;
  }
}

// ---------- threefry helpers ----------------------------------------------
__device__ __forceinline__ uint32_t rotl(uint32_t x, int r) {
  return __builtin_amdgcn_alignbit(x, x, (32 - r) & 31);
}
#define TF_ROUND4(r)                                            \
  { _Pragma("unroll") for (int j = 0; j < 4; ++j) {             \
      y0[j] += y1[j];                                           \
      y1[j] = rotl(y1[j], (r)) ^ y0[j];                         \
  } }
#define TF_INJ4(a, b)                                           \
  { _Pragma("unroll") for (int j = 0; j < 4; ++j) {             \
      y0[j] += (a); y1[j] += (b);                               \
  } }
#define TF_BODY                                                 \
  TF_ROUND4(13) TF_ROUND4(15) TF_ROUND4(26) TF_ROUND4(6)       \
  TF_INJ4(KS1, KS2 + 1u)                                        \
  TF_ROUND4(17) TF_ROUND4(29) TF_ROUND4(16) TF_ROUND4(24)      \
  TF_INJ4(KS2, 0u + 2u)                                         \
  TF_ROUND4(13) TF_ROUND4(15) TF_ROUND4(26) TF_ROUND4(6)       \
  TF_INJ4(0u, KS1 + 3u)                                         \
  TF_ROUND4(17) TF_ROUND4(29) TF_ROUND4(16) TF_ROUND4(24)      \
  TF_INJ4(KS1, KS2 + 4u)                                        \
  TF_ROUND4(13) TF_ROUND4(15) TF_ROUND4(26) TF_ROUND4(6)       \
  TF_INJ4(KS2, 0u + 5u)

// ---------- main (R6 structure: fused, block=256, 4 elems/thread) ---------
__global__ __launch_bounds__(256) void quantizer_channel_kernel(
    const float* __restrict__ x, const float* __restrict__ center,
    const float* __restrict__ ws, float* __restrict__ out, int n4)
{
  const int t = blockIdx.x * blockDim.x + threadIdx.x;
  if (t >= n4) return;

  const int lane   = threadIdx.x & 63;
  const int base_b = (lane & 48) << 2;           // bpermute base of own 16-group

  // per-lane crossbar tables (replicated every 16 lanes)
  const int ctab = __float_as_int(center[lane & 15]);            // idx -> value
  const int stab = (int)((const uint32_t*)ws)[16 + (lane & 15)]; // rank -> idx

  // thresholds (wave-uniform)
  const float4* wsf = (const float4*)ws;
  const float4 ta = wsf[0], tb = wsf[1], tc = wsf[2], td = wsf[3];
  const float T0 = ta.x, T1 = ta.y, T2  = ta.z, T3  = ta.w;
  const float T4 = tb.x, T5 = tb.y, T6  = tb.z, T7  = tb.w;
  const float T8 = tc.x, T9 = tc.y, T10 = tc.z, T11 = tc.w;
  const float T12 = td.x, T13 = td.y, T14 = td.z;

  const float4 xv = reinterpret_cast<const float4*>(x)[t];
  const float xe[4] = {xv.x, xv.y, xv.z, xv.w};
  float oe[4];
  const uint32_t cb = (uint32_t)t * 16u + KS1;   // counter base + ks1

#pragma unroll
  for (int e = 0; e < 4; ++e) {
    // ---- threefry2x32 x4 chains, counters (0, 16t+4e+j)
    uint32_t y0[4], y1[4];
    const uint32_t c0 = cb + 4u * (uint32_t)e;
#pragma unroll
    for (int j = 0; j < 4; ++j) { y0[j] = 0u; y1[j] = c0 + (uint32_t)j; }
    TF_BODY

    // ---- flip nibble, MSB-first
    const uint32_t f =
        (((y0[0] ^ y1[0]) < BERN_LT) ? 8u : 0u) |
        (((y0[1] ^ y1[1]) < BERN_LT) ? 4u : 0u) |
        (((y0[2] ^ y1[2]) < BERN_LT) ? 2u : 0u) |
        (((y0[3] ^ y1[3]) < BERN_LT) ? 1u : 0u);

    // ---- exact nearest-center: 4-level select tree over sorted cells
    const float v = xe[e];
    const bool b3_ = v > T7;
    const float s2 = b3_ ? T11 : T3;
    const bool b2_ = v > s2;
    const float s1 = b3_ ? (b2_ ? T13 : T9) : (b2_ ? T5 : T1);
    const bool b1_ = v > s1;
    const float u0 = b1_ ? T2  : T0;
    const float u1 = b1_ ? T6  : T4;
    const float u2 = b1_ ? T10 : T8;
    const float u3 = b1_ ? T14 : T12;
    const float s0 = b3_ ? (b2_ ? u3 : u2) : (b2_ ? u1 : u0);
    const bool b0_ = v > s0;
    const uint32_t cell = (b3_ ? 8u : 0u) | (b2_ ? 4u : 0u) |
                          (b1_ ? 2u : 0u) | (b0_ ? 1u : 0u);

    // rank -> orig idx, then noisy idx -> value: register crossbar, no VMEM
    const int best = __builtin_amdgcn_ds_bpermute(base_b + (int)(cell << 2), stab);
    const int fin_addr = base_b + (int)((((uint32_t)best) ^ f) << 2);
    oe[e] = __int_as_float(__builtin_amdgcn_ds_bpermute(fin_addr, ctab));
  }

  float4 o4;
  o4.x = oe[0]; o4.y = oe[1]; o4.z = oe[2]; o4.w = oe[3];
  reinterpret_cast<float4*>(out)[t] = o4;
}

extern "C" void kernel_launch(void* const* d_in, const int* in_sizes, int n_in,
                              void* d_out, int out_size, void* d_ws, size_t ws_size,
                              hipStream_t stream)
{
  const float* x      = (const float*)d_in[0];
  const float* center = (const float*)d_in[1];
  float* out          = (float*)d_out;
  float* ws           = (float*)d_ws;

  hipLaunchKernelGGL(quantizer_setup_kernel, dim3(1), dim3(64), 0, stream,
                     center, ws);

  const int N  = in_sizes[0];          // 8388608, divisible by 4
  const int n4 = N / 4;
  const int block = 256;
  const int grid  = (n4 + block - 1) / block;

  hipLaunchKernelGGL(quantizer_channel_kernel, dim3(grid), dim3(block), 0, stream,
                     x, center, ws, out, n4);
}